// Round 7
// baseline (138.198 us; speedup 1.0000x reference)
//
#include <hip/hip_runtime.h>
#include <hip/hip_bf16.h>
#include <stdint.h>

#define B_ 8
#define S_ 1024
#define NH_ 16
#define D_ 64
#define H_ 1024
#define M_TOT (B_*S_)
#define LOG2E 1.44269504088896f

typedef __attribute__((ext_vector_type(8))) short short8;
typedef __attribute__((ext_vector_type(4))) float f32x4;
typedef __attribute__((ext_vector_type(16))) float f32x16;

#if __has_builtin(__builtin_amdgcn_exp2f)
#define EXP2(x) __builtin_amdgcn_exp2f(x)
#else
#define EXP2(x) __expf((x) * 0.69314718056f)
#endif

static __device__ __forceinline__ unsigned short f2bf(float f) {
  union { float f; unsigned u; } c; c.f = f;
  unsigned u = c.u;
  return (unsigned short)((u + 0x7fffu + ((u >> 16) & 1u)) >> 16);
}

static __device__ __forceinline__ void gld_lds16(void* lds, const void* g) {
  __builtin_amdgcn_global_load_lds((const __attribute__((address_space(1))) unsigned*)g,
                                   (__attribute__((address_space(3))) unsigned*)lds, 16, 0, 0);
}

#define WAIT_LGKM0()  asm volatile("s_waitcnt lgkmcnt(0)" ::: "memory")
#define WAIT_VM(n)    asm volatile("s_waitcnt vmcnt(" #n ")" ::: "memory")
#define SBAR()        __builtin_amdgcn_s_barrier()
#define SCHED0()      __builtin_amdgcn_sched_barrier(0)
#define PRIO1()       __builtin_amdgcn_s_setprio(1)
#define PRIO0()       __builtin_amdgcn_s_setprio(0)

// ---------------- kernel 1: f32 -> bf16 conversion (X and the 3 weights) ----
__global__ void cvt_f32_bf16(const float* __restrict__ X,
                             const float* __restrict__ Wq,
                             const float* __restrict__ Wk,
                             const float* __restrict__ Wv,
                             unsigned short* __restrict__ Xbf,
                             unsigned short* __restrict__ Wbf) {
  const long long NX = (long long)M_TOT * H_;
  const long long NW = (long long)H_ * H_;
  long long t = (long long)blockIdx.x * blockDim.x + threadIdx.x;
  const long long stride = (long long)gridDim.x * blockDim.x;
  const long long total4 = (NX + 3 * NW) >> 2;
  for (; t < total4; t += stride) {
    long long e = t << 2;
    const float* src; unsigned short* dst;
    if (e < NX) { src = X + e; dst = Xbf + e; }
    else {
      long long r = e - NX;
      int w = (int)(r / NW);
      long long o = r - (long long)w * NW;
      src = (w == 0 ? Wq : (w == 1 ? Wk : Wv)) + o;
      dst = Wbf + (long long)w * NW + o;
    }
    float4 v = *(const float4*)src;
    ushort4 u;
    u.x = f2bf(v.x); u.y = f2bf(v.y); u.z = f2bf(v.z); u.w = f2bf(v.w);
    *(ushort4*)dst = u;
  }
}

// ---------------- kernel 2: QKV GEMM, 256x256x64, m201-style phases --------
// 8 waves: wm=w>>2 (2 M-halves of 128), wn=w&3 (4 N-strips of 64); per-wave
// output 128x64 = acc[8][4] (128 AGPR). Fragments capped at 64 arch VGPR:
//   P1 reads A-mh0(8)+B-nh0(4), P2 reads B-nh1(4), P3 reads A-mh1(8), P4 none.
// Per phase: {ds_reads | stage issues} SBAR lgkm(0) [16 MFMA prio-wrapped] SBAR.
// All 8 stage loads (tile t+1 -> nbuf) issue in P1/P2; single vmcnt(0) after
// P4's MFMA (~2 phases after last issue). 2-buffer 128KB LDS; every phase's
// ds_reads are lgkm-drained before its closing barrier -> WAR-safe.
// z=0:Q(scaled /8*log2e) z=1:K z=2:V^T via swapped operand roles.
#define QBM 256
#define QBN 256
#define QBK 64
#define ABYTES 32768
#define BUFSZ  65536

#define MMQ(I0, J0, AF, BF)                                               \
  _Pragma("unroll")                                                       \
  for (int a_ = 0; a_ < 4; ++a_)                                          \
    _Pragma("unroll")                                                     \
    for (int b_ = 0; b_ < 2; ++b_)                                        \
      _Pragma("unroll")                                                   \
      for (int k_ = 0; k_ < 2; ++k_)                                      \
        acc[(I0) + a_][(J0) + b_] = __builtin_amdgcn_mfma_f32_16x16x32_bf16( \
            AF[a_][k_], BF[b_][k_], acc[(I0) + a_][(J0) + b_], 0, 0, 0);

#define RD_A(BUF, MH)                                                     \
  _Pragma("unroll")                                                       \
  for (int f_ = 0; f_ < 4; ++f_)                                          \
    _Pragma("unroll")                                                     \
    for (int k_ = 0; k_ < 2; ++k_) A[f_][k_] = rdA(BUF, MH, f_, k_);

#define RD_B(DST, BUF, NH)                                                \
  _Pragma("unroll")                                                       \
  for (int f_ = 0; f_ < 2; ++f_)                                          \
    _Pragma("unroll")                                                     \
    for (int k_ = 0; k_ < 2; ++k_) DST[f_][k_] = rdB(BUF, NH, f_, k_);

__global__ __launch_bounds__(512, 1) void qkv_gemm(
    const unsigned short* __restrict__ Xbf,
    const unsigned short* __restrict__ Wbf,
    const float* __restrict__ bq, const float* __restrict__ bk,
    const float* __restrict__ bv,
    unsigned short* __restrict__ Qo, unsigned short* __restrict__ Ko,
    unsigned short* __restrict__ Vt) {
  __shared__ char lds[2 * BUFSZ];   // 128 KB

  const int tid = threadIdx.x;
  const int w = tid >> 6;
  const int l = tid & 63;
  const int lrow = l & 15, lgrp = l >> 4;
  const int wm = w >> 2, wn = w & 3;

  // XCD x owns m-tiles [4x,4x+4) x all 12 (n,z); nz-major within XCD.
  const int orig = blockIdx.x;          // 0..383
  const int xcd = orig & 7;
  const int slot = orig >> 3;           // 0..47
  const int nz = slot >> 2;             // 0..11
  const int mtile = (xcd * 4 + (slot & 3)) * QBM;
  const int ntile = (nz & 3) * QBN;
  const int z = nz >> 2;

  const unsigned short* Wz = Wbf + (long long)z * H_ * H_;

  const int srow = l >> 3;
  const int sslot = l & 7;
  auto stageA = [&](char* buf, int j, int k0) {
    int row = j * 8 + srow;
    int so = (sslot ^ (row & 7)) * 8;
    gld_lds16(buf + j * 1024, Xbf + (long long)(mtile + row) * H_ + k0 + so);
  };
  auto stageB = [&](char* buf, int j, int k0) {
    int row = j * 8 + srow;
    int so = (sslot ^ (row & 7)) * 8;
    gld_lds16(buf + ABYTES + j * 1024, Wz + (long long)(ntile + row) * H_ + k0 + so);
  };

  const int offA = (z == 2) ? ABYTES : 0;
  const int offB = (z == 2) ? 0 : ABYTES;
  auto rdA = [&](const char* buf, int mh, int fi, int ks) -> short8 {
    int r = wm * 128 + mh * 64 + fi * 16 + lrow;
    return *(const short8*)(buf + offA + r * 128 + (((ks * 4 + lgrp) ^ (r & 7)) * 16));
  };
  auto rdB = [&](const char* buf, int nh, int fi, int ks) -> short8 {
    int r = wn * 64 + nh * 32 + fi * 16 + lrow;
    return *(const short8*)(buf + offB + r * 128 + (((ks * 4 + lgrp) ^ (r & 7)) * 16));
  };

  f32x4 acc[8][4];
  f32x4 zero = {0.f, 0.f, 0.f, 0.f};
  #pragma unroll
  for (int a = 0; a < 8; ++a)
    #pragma unroll
    for (int c = 0; c < 4; ++c) acc[a][c] = zero;

  short8 A[4][2], B0[2][2], B1[2][2];

  // prologue: stage tile 0 into buf0, drain, publish
  #pragma unroll
  for (int c = 0; c < 4; ++c) stageA(lds, w * 4 + c, 0);
  #pragma unroll
  for (int c = 0; c < 4; ++c) stageB(lds, w * 4 + c, 0);
  SCHED0(); WAIT_VM(0); SCHED0();
  SBAR();

  #pragma unroll 1
  for (int t = 0; t < 16; ++t) {
    char* buf  = lds + ((t & 1) ? BUFSZ : 0);
    char* nbuf = lds + ((t & 1) ? 0 : BUFSZ);
    const bool st = (t < 15);
    const int k0n = (t + 1) * QBK;

    // ---- P1: reads A-mh0 + B-nh0; stage next-tile A; MFMA (mh0,nh0)
    RD_A(buf, 0);
    RD_B(B0, buf, 0);
    if (st) {
      stageA(nbuf, w * 4 + 0, k0n); stageA(nbuf, w * 4 + 1, k0n);
      stageA(nbuf, w * 4 + 2, k0n); stageA(nbuf, w * 4 + 3, k0n);
    }
    SBAR();
    WAIT_LGKM0(); SCHED0();
    PRIO1(); MMQ(0, 0, A, B0); PRIO0();
    SBAR();

    // ---- P2: reads B-nh1; stage next-tile B; MFMA (mh0,nh1)
    RD_B(B1, buf, 1);
    if (st) {
      stageB(nbuf, w * 4 + 0, k0n); stageB(nbuf, w * 4 + 1, k0n);
      stageB(nbuf, w * 4 + 2, k0n); stageB(nbuf, w * 4 + 3, k0n);
    }
    SBAR();
    WAIT_LGKM0(); SCHED0();
    PRIO1(); MMQ(0, 2, A, B1); PRIO0();
    SBAR();

    // ---- P3: reads A-mh1; MFMA (mh1,nh1)
    RD_A(buf, 1);
    SBAR();
    WAIT_LGKM0(); SCHED0();
    PRIO1(); MMQ(4, 2, A, B1); PRIO0();
    SBAR();

    // ---- P4: no reads; MFMA (mh1,nh0); boundary vm-drain AFTER compute
    PRIO1(); MMQ(4, 0, A, B0); PRIO0();
    if (st) { SCHED0(); WAIT_VM(0); SCHED0(); }
    SBAR();
  }

  // ---- epilogue (verbatim, numerically verified R5/R6)
  const float* bias = (z == 0) ? bq : (z == 1) ? bk : bv;
  if (z != 2) {
    unsigned short* O = (z == 0) ? Qo : Ko;
    #pragma unroll
    for (int in = 0; in < 4; ++in) {
      int n = ntile + wn * 64 + in * 16 + lrow;
      float bv_ = bias[n];
      int h = n >> 6, d = n & 63;
      #pragma unroll
      for (int im = 0; im < 8; ++im)
        #pragma unroll
        for (int r = 0; r < 4; ++r) {
          int m = mtile + wm * 128 + im * 16 + lgrp * 4 + r;
          float val = acc[im][in][r] + bv_;
          if (z == 0) val *= 0.125f * LOG2E;
          int b = m >> 10, s = m & 1023;
          O[(((long long)(b * NH_ + h)) * S_ + s) * D_ + d] = f2bf(val);
        }
    }
  } else {
    #pragma unroll
    for (int im = 0; im < 8; ++im)
      #pragma unroll
      for (int r = 0; r < 4; ++r) {
        int nfull = ntile + wm * 128 + im * 16 + lgrp * 4 + r;   // d-side (W rows)
        float bv_ = bias[nfull];
        int h = nfull >> 6, d = nfull & 63;
        #pragma unroll
        for (int in = 0; in < 4; ++in) {
          int mfull = mtile + wn * 64 + in * 16 + lrow;           // s-side (X rows)
          float val = acc[im][in][r] + bv_;
          int b = mfull >> 10, s = mfull & 1023;
          Vt[(((long long)(b * NH_ + h)) * D_ + d) * S_ + s] = f2bf(val);
        }
      }
  }
}

// ---------------- kernel 3: fused flash attention (32x32 swapped) ----------
__global__ __launch_bounds__(256, 2) void attn_fused(
    const unsigned short* __restrict__ Qbf,
    const unsigned short* __restrict__ Kbf,
    const unsigned short* __restrict__ Vtb,
    const float* __restrict__ mask,
    float* __restrict__ out) {
  __shared__ char lds[32768];                 // 2 x (K 8KB | V^T 8KB)
  const int tid = threadIdx.x, w = tid >> 6, l = tid & 63;
  const int l31 = l & 31, h = l >> 5;

  const int lid = blockIdx.x;                 // 0..511
  const int xcd = lid & 7, k8 = lid >> 3;
  const int bh = xcd * 16 + (k8 >> 2);
  const int qt = k8 & 3;
  const int b = bh >> 4, hd = bh & 15;
  const int q0 = qt * 256 + w * 64;

  const unsigned short* Kg = Kbf + (long long)bh * S_ * D_;
  const unsigned short* Vg = Vtb + (long long)bh * D_ * S_;
  const float* mrow = mask + b * S_;

  {
    const int row = (w * 2) * 8 + (l >> 3);
    const int row1 = (w * 2 + 1) * 8 + (l >> 3);
    const int so = ((l & 7) ^ (row & 7)) * 8;
    const int so1 = ((l & 7) ^ (row1 & 7)) * 8;
    gld_lds16(lds + (w * 2) * 1024,        Kg + (long long)row * D_ + so);
    gld_lds16(lds + (w * 2 + 1) * 1024,    Kg + (long long)row1 * D_ + so1);
    gld_lds16(lds + 8192 + (w * 2) * 1024, Vg + (long long)row * S_ + so);
    gld_lds16(lds + 8192 + (w * 2 + 1) * 1024, Vg + (long long)row1 * S_ + so1);
  }

  short8 qf[2][4];
  #pragma unroll
  for (int qb = 0; qb < 2; ++qb)
    #pragma unroll
    for (int ks = 0; ks < 4; ++ks)
      qf[qb][ks] = *(const short8*)(Qbf + ((long long)bh * S_ + q0 + qb * 32 + l31) * D_ + ks * 16 + 8 * h);

  f32x16 acc[2][2];
  #pragma unroll
  for (int db = 0; db < 2; ++db)
    #pragma unroll
    for (int qb = 0; qb < 2; ++qb)
      #pragma unroll
      for (int r = 0; r < 16; ++r) acc[db][qb][r] = 0.f;
  float m_run[2] = {-1e30f, -1e30f};
  float l_run[2] = {0.f, 0.f};

  __syncthreads();

  for (int kt = 0; kt < S_ / 64; ++kt) {
    const int p = kt & 1;
    char* ldsK = lds + p * 16384;
    char* ldsV = ldsK + 8192;
    const int key0 = kt * 64;

    if (kt < S_ / 64 - 1) {
      char* nb = lds + (p ^ 1) * 16384;
      const int nk0 = key0 + 64;
      #pragma unroll
      for (int t = 0; t < 2; ++t) {
        int j = w * 2 + t;
        int row = j * 8 + (l >> 3);
        int so = ((l & 7) ^ (row & 7)) * 8;
        gld_lds16(nb + j * 1024,        Kg + (long long)(nk0 + row) * D_ + so);
        gld_lds16(nb + 8192 + j * 1024, Vg + (long long)row * S_ + nk0 + so);
      }
    }

    f32x16 sc[2][2];
    #pragma unroll
    for (int kb = 0; kb < 2; ++kb)
      #pragma unroll
      for (int qb = 0; qb < 2; ++qb)
        #pragma unroll
        for (int r = 0; r < 16; ++r) sc[kb][qb][r] = 0.f;

    #pragma unroll
    for (int kb = 0; kb < 2; ++kb) {
      short8 kf[4];
      #pragma unroll
      for (int ks = 0; ks < 4; ++ks) {
        int row = kb * 32 + l31;
        int g = (2 * ks + h) ^ (row & 7);
        kf[ks] = *(const short8*)(ldsK + row * 128 + g * 16);
      }
      __builtin_amdgcn_s_setprio(1);
      #pragma unroll
      for (int qb = 0; qb < 2; ++qb)
        #pragma unroll
        for (int ks = 0; ks < 4; ++ks)
          sc[kb][qb] = __builtin_amdgcn_mfma_f32_32x32x16_bf16(
              kf[ks], qf[qb][ks], sc[kb][qb], 0, 0, 0);
      __builtin_amdgcn_s_setprio(0);
    }

    short8 pfrag[2][4];
    #pragma unroll
    for (int qb = 0; qb < 2; ++qb) {
      float sv[32];
      #pragma unroll
      for (int kb = 0; kb < 2; ++kb)
        #pragma unroll
        for (int rg = 0; rg < 4; ++rg) {
          f32x4 m4 = *(const f32x4*)(mrow + key0 + kb * 32 + rg * 8 + 4 * h);
          #pragma unroll
          for (int c = 0; c < 4; ++c)
            sv[kb * 16 + rg * 4 + c] = fmaf(m4[c], LOG2E, sc[kb][qb][rg * 4 + c]);
        }
      float r16[16];
      #pragma unroll
      for (int i = 0; i < 16; ++i) r16[i] = fmaxf(sv[i], sv[i + 16]);
      #pragma unroll
      for (int i = 0; i < 8; ++i) r16[i] = fmaxf(r16[i], r16[i + 8]);
      #pragma unroll
      for (int i = 0; i < 4; ++i) r16[i] = fmaxf(r16[i], r16[i + 4]);
      float pm = fmaxf(fmaxf(r16[0], r16[1]), fmaxf(r16[2], r16[3]));
      pm = fmaxf(pm, __shfl_xor(pm, 32));
      if (!__all(pm - m_run[qb] <= 11.5f)) {
        float mn = fmaxf(m_run[qb], pm);
        float rs = EXP2(m_run[qb] - mn);
        m_run[qb] = mn;
        l_run[qb] *= rs;
        #pragma unroll
        for (int db = 0; db < 2; ++db)
          #pragma unroll
          for (int r = 0; r < 16; ++r) acc[db][qb][r] *= rs;
      }
      const float mcur = m_run[qb];
      #pragma unroll
      for (int i = 0; i < 32; ++i) sv[i] = EXP2(sv[i] - mcur);
      #pragma unroll
      for (int i = 0; i < 16; ++i) r16[i] = sv[i] + sv[i + 16];
      #pragma unroll
      for (int i = 0; i < 8; ++i) r16[i] = r16[i] + r16[i + 8];
      #pragma unroll
      for (int i = 0; i < 4; ++i) r16[i] = r16[i] + r16[i + 4];
      float ps = (r16[0] + r16[1]) + (r16[2] + r16[3]);
      ps += __shfl_xor(ps, 32);
      l_run[qb] += ps;

      unsigned Wd[8][2];
      #pragma unroll
      for (int j = 0; j < 8; ++j) {
        int base = (j >> 2) * 16 + (j & 3) * 4;
        asm("v_cvt_pk_bf16_f32 %0, %1, %2" : "=v"(Wd[j][0]) : "v"(sv[base + 0]), "v"(sv[base + 1]));
        asm("v_cvt_pk_bf16_f32 %0, %1, %2" : "=v"(Wd[j][1]) : "v"(sv[base + 2]), "v"(sv[base + 3]));
      }
      #pragma unroll
      for (int ks = 0; ks < 4; ++ks) {
        unsigned s0 = h ? Wd[2 * ks][0] : Wd[2 * ks + 1][0];
        unsigned s1 = h ? Wd[2 * ks][1] : Wd[2 * ks + 1][1];
        unsigned r0 = __shfl_xor(s0, 32);
        unsigned r1 = __shfl_xor(s1, 32);
        unsigned o0 = h ? Wd[2 * ks + 1][0] : Wd[2 * ks][0];
        unsigned o1 = h ? Wd[2 * ks + 1][1] : Wd[2 * ks][1];
        union { unsigned u[4]; short8 s; } fu;
        fu.u[0] = h ? r0 : o0;
        fu.u[1] = h ? r1 : o1;
        fu.u[2] = h ? o0 : r0;
        fu.u[3] = h ? o1 : r1;
        pfrag[qb][ks] = fu.s;
      }
    }

    #pragma unroll
    for (int db = 0; db < 2; ++db) {
      short8 vf[4];
      #pragma unroll
      for (int ks = 0; ks < 4; ++ks) {
        int row = db * 32 + l31;
        int g = (2 * ks + h) ^ (row & 7);
        vf[ks] = *(const short8*)(ldsV + row * 128 + g * 16);
      }
      __builtin_amdgcn_s_setprio(1);
      #pragma unroll
      for (int qb = 0; qb < 2; ++qb)
        #pragma unroll
        for (int ks = 0; ks < 4; ++ks)
          acc[db][qb] = __builtin_amdgcn_mfma_f32_32x32x16_bf16(
              vf[ks], pfrag[qb][ks], acc[db][qb], 0, 0, 0);
      __builtin_amdgcn_s_setprio(0);
    }

    __syncthreads();
  }

  #pragma unroll
  for (int qb = 0; qb < 2; ++qb) {
    float inv = 1.0f / l_run[qb];
    int q = q0 + qb * 32 + l31;
    float* orow = out + ((long long)b * S_ + q) * H_ + hd * D_;
    #pragma unroll
    for (int db = 0; db < 2; ++db)
      #pragma unroll
      for (int rg = 0; rg < 4; ++rg) {
        f32x4 v4;
        #pragma unroll
        for (int c = 0; c < 4; ++c) v4[c] = acc[db][qb][rg * 4 + c] * inv;
        *(f32x4*)(orow + db * 32 + rg * 8 + 4 * h) = v4;
      }
  }
}

// ---------------- launcher -------------------------------------------------
extern "C" void kernel_launch(void* const* d_in, const int* in_sizes, int n_in,
                              void* d_out, int out_size, void* d_ws, size_t ws_size,
                              hipStream_t stream) {
  const float* X    = (const float*)d_in[0];
  const float* mask = (const float*)d_in[1];
  const float* Wq   = (const float*)d_in[2];
  const float* bq   = (const float*)d_in[3];
  const float* Wk   = (const float*)d_in[4];
  const float* bk   = (const float*)d_in[5];
  const float* Wv   = (const float*)d_in[6];
  const float* bv   = (const float*)d_in[7];
  float* out = (float*)d_out;

  char* ws = (char*)d_ws;
  unsigned short* Xbf = (unsigned short*)ws;                 // 16 MB
  unsigned short* Wbf = (unsigned short*)(ws + 16777216);    //  6 MB
  unsigned short* Qb  = (unsigned short*)(ws + 23068672);    // 16 MB
  unsigned short* Kb  = (unsigned short*)(ws + 39845888);    // 16 MB
  unsigned short* Vt  = (unsigned short*)(ws + 56623104);    // 16 MB

  hipLaunchKernelGGL(cvt_f32_bf16, dim3(2048), dim3(256), 0, stream,
                     X, Wq, Wk, Wv, Xbf, Wbf);
  hipLaunchKernelGGL(qkv_gemm, dim3(384), dim3(512), 0, stream,
                     Xbf, Wbf, bq, bk, bv, Qb, Kb, Vt);
  hipLaunchKernelGGL(attn_fused, dim3(512), dim3(256), 0, stream,
                     Qb, Kb, Vt, mask, out);
}

// Round 8
// 133.026 us; speedup vs baseline: 1.0389x; 1.0389x over previous
//
#include <hip/hip_runtime.h>
#include <hip/hip_bf16.h>
#include <stdint.h>

#define B_ 8
#define S_ 1024
#define NH_ 16
#define D_ 64
#define H_ 1024
#define M_TOT (B_*S_)
#define LOG2E 1.44269504088896f

typedef __attribute__((ext_vector_type(8))) short short8;
typedef __attribute__((ext_vector_type(4))) float f32x4;
typedef __attribute__((ext_vector_type(16))) float f32x16;

#if __has_builtin(__builtin_amdgcn_exp2f)
#define EXP2(x) __builtin_amdgcn_exp2f(x)
#else
#define EXP2(x) __expf((x) * 0.69314718056f)
#endif

static __device__ __forceinline__ unsigned short f2bf(float f) {
  union { float f; unsigned u; } c; c.f = f;
  unsigned u = c.u;
  return (unsigned short)((u + 0x7fffu + ((u >> 16) & 1u)) >> 16);
}

static __device__ __forceinline__ void gld_lds16(void* lds, const void* g) {
  __builtin_amdgcn_global_load_lds((const __attribute__((address_space(1))) unsigned*)g,
                                   (__attribute__((address_space(3))) unsigned*)lds, 16, 0, 0);
}

#define WAIT_LGKM0() asm volatile("s_waitcnt lgkmcnt(0)" ::: "memory")
#define WAIT_VM(n)   asm volatile("s_waitcnt vmcnt(" #n ")" ::: "memory")
#define SBAR()       __builtin_amdgcn_s_barrier()
#define SCHED0()     __builtin_amdgcn_sched_barrier(0)

// ---------------- kernel 1: f32 -> bf16 conversion (X and the 3 weights) ----
__global__ void cvt_f32_bf16(const float* __restrict__ X,
                             const float* __restrict__ Wq,
                             const float* __restrict__ Wk,
                             const float* __restrict__ Wv,
                             unsigned short* __restrict__ Xbf,
                             unsigned short* __restrict__ Wbf) {
  const long long NX = (long long)M_TOT * H_;
  const long long NW = (long long)H_ * H_;
  long long t = (long long)blockIdx.x * blockDim.x + threadIdx.x;
  const long long stride = (long long)gridDim.x * blockDim.x;
  const long long total4 = (NX + 3 * NW) >> 2;
  for (; t < total4; t += stride) {
    long long e = t << 2;
    const float* src; unsigned short* dst;
    if (e < NX) { src = X + e; dst = Xbf + e; }
    else {
      long long r = e - NX;
      int w = (int)(r / NW);
      long long o = r - (long long)w * NW;
      src = (w == 0 ? Wq : (w == 1 ? Wk : Wv)) + o;
      dst = Wbf + (long long)w * NW + o;
    }
    float4 v = *(const float4*)src;
    ushort4 u;
    u.x = f2bf(v.x); u.y = f2bf(v.y); u.z = f2bf(v.z); u.w = f2bf(v.w);
    *(ushort4*)dst = u;
  }
}

// ---------------- kernel 2: QKV GEMM (R4 verbatim — best measured 66.6us) --
// Tile 128(M) x 256(N) x 64(K). 8 waves: wm=w>>2 (2 M-strips of 64),
// wn=w&3 (4 N-strips of 64). Per-wave output 64x64 = acc[4][4] 16x16 frags.
// 3 LDS buffers (48KB: A 16KB rows0..127 | B 32KB rows0..255).
// Per-wave ledger: 6 loads/tile (A:2, B:4). Tile t lives in buf t%3; during
// tile t we stage tile t+2 (3 loads per phase). Boundary vmcnt(6) waits
// tile t+1's 6 loads, leaves t+2's 6 in flight. 2 phases/tile, 16 MFMA each.
// z=0:Q (scaled /8*log2e) z=1:K  z=2:V^T via swapped operand roles.
#define QBM 128
#define QBN 256
#define QBK 64
#define BUFSZ 49152

__global__ __launch_bounds__(512, 2) void qkv_gemm(
    const unsigned short* __restrict__ Xbf,
    const unsigned short* __restrict__ Wbf,
    const float* __restrict__ bq, const float* __restrict__ bk,
    const float* __restrict__ bv,
    unsigned short* __restrict__ Qo, unsigned short* __restrict__ Ko,
    unsigned short* __restrict__ Vt) {
  __shared__ char lds[3 * BUFSZ];   // 144 KB

  const int tid = threadIdx.x;
  const int w = tid >> 6;
  const int l = tid & 63;
  const int lrow = l & 15, lgrp = l >> 4;
  const int wm = w >> 2, wn = w & 3;

  // L2-correct swizzle: 768 blocks = 3 rounds x 256. XCD x (=orig&7) in
  // round z owns m-tiles [8x,8x+8) x all 4 n-tiles.
  const int orig = blockIdx.x;
  const int xcd = orig & 7;
  const int slot = orig >> 3;          // 0..95
  const int z = slot >> 5;             // 0..2 (round)
  const int i = slot & 31;
  const int mtile = (xcd * 8 + (i >> 2)) * QBM;
  const int ntile = (i & 3) * QBN;

  const unsigned short* Wz = Wbf + (long long)z * H_ * H_;

  const int srow = l >> 3;
  const int sslot = l & 7;
  auto stageA = [&](char* buf, int j, int k0) {
    int row = j * 8 + srow;
    int so = (sslot ^ (row & 7)) * 8;
    gld_lds16(buf + j * 1024, Xbf + (long long)(mtile + row) * H_ + k0 + so);
  };
  auto stageB = [&](char* buf, int j, int k0) {
    int row = j * 8 + srow;
    int so = (sslot ^ (row & 7)) * 8;
    gld_lds16(buf + 16384 + j * 1024, Wz + (long long)(ntile + row) * H_ + k0 + so);
  };

  const int strA = (z == 2 ? wn : wm) * 64;
  const int strB = (z == 2 ? wm : wn) * 64;
  const int offA = (z == 2) ? 16384 : 0;
  const int offB = (z == 2) ? 0 : 16384;
  auto rdA = [&](char* buf, int fi, int ks) -> short8 {
    int r = strA + fi * 16 + lrow;
    return *(const short8*)(buf + offA + r * 128 + (((ks * 4 + lgrp) ^ (r & 7)) * 16));
  };
  auto rdB = [&](char* buf, int fi, int ks) -> short8 {
    int r = strB + fi * 16 + lrow;
    return *(const short8*)(buf + offB + r * 128 + (((ks * 4 + lgrp) ^ (r & 7)) * 16));
  };

  f32x4 acc[4][4];
  f32x4 zero = {0.f, 0.f, 0.f, 0.f};
  #pragma unroll
  for (int a = 0; a < 4; ++a)
    #pragma unroll
    for (int c = 0; c < 4; ++c) acc[a][c] = zero;

  // prologue: stage tiles 0 (buf0) and 1 (buf1); 6 loads each per wave
  {
    char* b0p = lds;
    char* b1p = lds + BUFSZ;
    stageA(b0p, 2 * w + 0, 0); stageA(b0p, 2 * w + 1, 0);
    #pragma unroll
    for (int c = 0; c < 4; ++c) stageB(b0p, 4 * w + c, 0);
    stageA(b1p, 2 * w + 0, QBK); stageA(b1p, 2 * w + 1, QBK);
    #pragma unroll
    for (int c = 0; c < 4; ++c) stageB(b1p, 4 * w + c, QBK);
  }
  WAIT_VM(6);     // tile 0 resident (my 6 oldest), tile 1 in flight
  SBAR();

  #pragma unroll 1
  for (int t = 0; t < 16; ++t) {
    char* buf  = lds + (t % 3) * BUFSZ;
    char* nbuf = lds + ((t + 2) % 3) * BUFSZ;
    const int k0n = (t + 2) * QBK;
    const bool st = (t + 2 < 16);

    short8 af[4][2], bf[2][2];

    // ---- phase 1: n-half 0  (12 ds_read, 16 MFMA)
    #pragma unroll
    for (int fi = 0; fi < 4; ++fi)
      #pragma unroll
      for (int ks = 0; ks < 2; ++ks) af[fi][ks] = rdA(buf, fi, ks);
    #pragma unroll
    for (int fi = 0; fi < 2; ++fi)
      #pragma unroll
      for (int ks = 0; ks < 2; ++ks) bf[fi][ks] = rdB(buf, fi, ks);
    if (st) { stageA(nbuf, 2 * w + 0, k0n); stageA(nbuf, 2 * w + 1, k0n);
              stageB(nbuf, 4 * w + 0, k0n); }
    SBAR();
    WAIT_LGKM0(); SCHED0();
    __builtin_amdgcn_s_setprio(1);
    #pragma unroll
    for (int im = 0; im < 4; ++im)
      #pragma unroll
      for (int in = 0; in < 2; ++in)
        #pragma unroll
        for (int ks = 0; ks < 2; ++ks)
          acc[im][in] = __builtin_amdgcn_mfma_f32_16x16x32_bf16(
              af[im][ks], bf[in][ks], acc[im][in], 0, 0, 0);
    __builtin_amdgcn_s_setprio(0);
    SBAR();

    // ---- phase 2: n-half 1  (4 ds_read, 16 MFMA; af regs stay live)
    #pragma unroll
    for (int fi = 0; fi < 2; ++fi)
      #pragma unroll
      for (int ks = 0; ks < 2; ++ks) bf[fi][ks] = rdB(buf, 2 + fi, ks);
    if (st) { stageB(nbuf, 4 * w + 1, k0n); stageB(nbuf, 4 * w + 2, k0n);
              stageB(nbuf, 4 * w + 3, k0n); }
    SBAR();
    WAIT_LGKM0(); SCHED0();
    __builtin_amdgcn_s_setprio(1);
    #pragma unroll
    for (int im = 0; im < 4; ++im)
      #pragma unroll
      for (int in = 0; in < 2; ++in)
        #pragma unroll
        for (int ks = 0; ks < 2; ++ks)
          acc[im][2 + in] = __builtin_amdgcn_mfma_f32_16x16x32_bf16(
              af[im][ks], bf[in][ks], acc[im][2 + in], 0, 0, 0);
    __builtin_amdgcn_s_setprio(0);
    if (t < 14) { WAIT_VM(6); } else { WAIT_VM(0); }
    SBAR();
  }

  // ---- epilogue
  const float* bias = (z == 0) ? bq : (z == 1) ? bk : bv;
  if (z != 2) {
    unsigned short* O = (z == 0) ? Qo : Ko;
    #pragma unroll
    for (int in = 0; in < 4; ++in) {
      int n = ntile + wn * 64 + in * 16 + lrow;
      float bv_ = bias[n];
      int h = n >> 6, d = n & 63;
      #pragma unroll
      for (int im = 0; im < 4; ++im)
        #pragma unroll
        for (int r = 0; r < 4; ++r) {
          int m = mtile + wm * 64 + im * 16 + lgrp * 4 + r;
          float val = acc[im][in][r] + bv_;
          if (z == 0) val *= 0.125f * LOG2E;
          int b = m >> 10, s = m & 1023;
          O[(((long long)(b * NH_ + h)) * S_ + s) * D_ + d] = f2bf(val);
        }
    }
  } else {
    #pragma unroll
    for (int im = 0; im < 4; ++im)
      #pragma unroll
      for (int r = 0; r < 4; ++r) {
        int nfull = ntile + wn * 64 + im * 16 + lgrp * 4 + r;   // d-side (W rows)
        float bv_ = bias[nfull];
        int h = nfull >> 6, d = nfull & 63;
        #pragma unroll
        for (int in = 0; in < 4; ++in) {
          int mfull = mtile + wm * 64 + in * 16 + lrow;          // s-side (X rows)
          float val = acc[im][in][r] + bv_;
          int b = mfull >> 10, s = mfull & 1023;
          Vt[(((long long)(b * NH_ + h)) * D_ + d) * S_ + s] = f2bf(val);
        }
      }
  }
}

// ---------------- kernel 3: fused flash attention (depth-2 pipeline) -------
// 3 x 16KB KV buffers + 4KB mask row in LDS. Per wave per tile: exactly 4
// gld_lds (clean vmcnt ledger; mask reads are ds_read, qf preloaded+drained).
// Tile t: stage t+2 -> buf[(t+2)%3]; compute on buf[t%3]; end: vmcnt(4)
// (waits t+1, leaves t+2 in flight) + raw s_barrier.
__global__ __launch_bounds__(256, 2) void attn_fused(
    const unsigned short* __restrict__ Qbf,
    const unsigned short* __restrict__ Kbf,
    const unsigned short* __restrict__ Vtb,
    const float* __restrict__ mask,
    float* __restrict__ out) {
  __shared__ char lds[3 * 16384 + 4096];      // 3 KV buffers | mask row
  char* ldsM = lds + 49152;
  const int tid = threadIdx.x, w = tid >> 6, l = tid & 63;
  const int l31 = l & 31, h = l >> 5;

  const int lid = blockIdx.x;                 // 0..511
  const int xcd = lid & 7, k8 = lid >> 3;
  const int bh = xcd * 16 + (k8 >> 2);
  const int qt = k8 & 3;
  const int b = bh >> 4, hd = bh & 15;
  const int q0 = qt * 256 + w * 64;

  const unsigned short* Kg = Kbf + (long long)bh * S_ * D_;
  const unsigned short* Vg = Vtb + (long long)bh * D_ * S_;
  const float* mrow = mask + b * S_;

  auto stageKV = [&](int kt, char* buf) {
    const int key0 = kt * 64;
    #pragma unroll
    for (int t = 0; t < 2; ++t) {
      int j = w * 2 + t;
      int row = j * 8 + (l >> 3);
      int so = ((l & 7) ^ (row & 7)) * 8;
      gld_lds16(buf + j * 1024,        Kg + (long long)(key0 + row) * D_ + so);
      gld_lds16(buf + 8192 + j * 1024, Vg + (long long)row * S_ + key0 + so);
    }
  };

  // ---- prologue: qf + mask loads, drain, then pipelined staging of t0,t1
  short8 qf[2][4];
  #pragma unroll
  for (int qb = 0; qb < 2; ++qb)
    #pragma unroll
    for (int ks = 0; ks < 4; ++ks)
      qf[qb][ks] = *(const short8*)(Qbf + ((long long)bh * S_ + q0 + qb * 32 + l31) * D_ + ks * 16 + 8 * h);
  gld_lds16(ldsM + w * 1024, mrow + w * 256 + l * 4);   // mask row -> LDS
  SCHED0(); WAIT_VM(0); SCHED0();                        // qf + mask resident

  stageKV(0, lds);
  stageKV(1, lds + 16384);
  SCHED0(); WAIT_VM(4); SCHED0();                        // tile 0 resident
  SBAR();

  f32x16 acc[2][2];
  #pragma unroll
  for (int db = 0; db < 2; ++db)
    #pragma unroll
    for (int qb = 0; qb < 2; ++qb)
      #pragma unroll
      for (int r = 0; r < 16; ++r) acc[db][qb][r] = 0.f;
  float m_run[2] = {-1e30f, -1e30f};
  float l_run[2] = {0.f, 0.f};

  #pragma unroll 1
  for (int kt = 0; kt < S_ / 64; ++kt) {
    char* ldsK = lds + (kt % 3) * 16384;
    char* ldsV = ldsK + 8192;
    const int key0 = kt * 64;
    const bool st = (kt + 2 < S_ / 64);

    if (st) stageKV(kt + 2, lds + ((kt + 2) % 3) * 16384);

    // ---- QK^T (swapped): sc[kb][qb] = S^T
    f32x16 sc[2][2];
    #pragma unroll
    for (int kb = 0; kb < 2; ++kb)
      #pragma unroll
      for (int qb = 0; qb < 2; ++qb)
        #pragma unroll
        for (int r = 0; r < 16; ++r) sc[kb][qb][r] = 0.f;

    #pragma unroll
    for (int kb = 0; kb < 2; ++kb) {
      short8 kf[4];
      #pragma unroll
      for (int ks = 0; ks < 4; ++ks) {
        int row = kb * 32 + l31;
        int g = (2 * ks + h) ^ (row & 7);
        kf[ks] = *(const short8*)(ldsK + row * 128 + g * 16);
      }
      __builtin_amdgcn_s_setprio(1);
      #pragma unroll
      for (int qb = 0; qb < 2; ++qb)
        #pragma unroll
        for (int ks = 0; ks < 4; ++ks)
          sc[kb][qb] = __builtin_amdgcn_mfma_f32_32x32x16_bf16(
              kf[ks], qf[qb][ks], sc[kb][qb], 0, 0, 0);
      __builtin_amdgcn_s_setprio(0);
    }

    // ---- softmax per q-block (mask from LDS; lane owns q = l&31)
    short8 pfrag[2][4];
    #pragma unroll
    for (int qb = 0; qb < 2; ++qb) {
      float sv[32];
      #pragma unroll
      for (int kb = 0; kb < 2; ++kb)
        #pragma unroll
        for (int rg = 0; rg < 4; ++rg) {
          f32x4 m4 = *(const f32x4*)(ldsM + (key0 + kb * 32 + rg * 8 + 4 * h) * 4);
          #pragma unroll
          for (int c = 0; c < 4; ++c)
            sv[kb * 16 + rg * 4 + c] = fmaf(m4[c], LOG2E, sc[kb][qb][rg * 4 + c]);
        }
      float r16[16];
      #pragma unroll
      for (int i = 0; i < 16; ++i) r16[i] = fmaxf(sv[i], sv[i + 16]);
      #pragma unroll
      for (int i = 0; i < 8; ++i) r16[i] = fmaxf(r16[i], r16[i + 8]);
      #pragma unroll
      for (int i = 0; i < 4; ++i) r16[i] = fmaxf(r16[i], r16[i + 4]);
      float pm = fmaxf(fmaxf(r16[0], r16[1]), fmaxf(r16[2], r16[3]));
      pm = fmaxf(pm, __shfl_xor(pm, 32));
      if (!__all(pm - m_run[qb] <= 11.5f)) {
        float mn = fmaxf(m_run[qb], pm);
        float rs = EXP2(m_run[qb] - mn);
        m_run[qb] = mn;
        l_run[qb] *= rs;
        #pragma unroll
        for (int db = 0; db < 2; ++db)
          #pragma unroll
          for (int r = 0; r < 16; ++r) acc[db][qb][r] *= rs;
      }
      const float mcur = m_run[qb];
      #pragma unroll
      for (int i = 0; i < 32; ++i) sv[i] = EXP2(sv[i] - mcur);
      #pragma unroll
      for (int i = 0; i < 16; ++i) r16[i] = sv[i] + sv[i + 16];
      #pragma unroll
      for (int i = 0; i < 8; ++i) r16[i] = r16[i] + r16[i + 8];
      #pragma unroll
      for (int i = 0; i < 4; ++i) r16[i] = r16[i] + r16[i + 4];
      float ps = (r16[0] + r16[1]) + (r16[2] + r16[3]);
      ps += __shfl_xor(ps, 32);
      l_run[qb] += ps;

      unsigned Wd[8][2];
      #pragma unroll
      for (int j = 0; j < 8; ++j) {
        int base = (j >> 2) * 16 + (j & 3) * 4;
        asm("v_cvt_pk_bf16_f32 %0, %1, %2" : "=v"(Wd[j][0]) : "v"(sv[base + 0]), "v"(sv[base + 1]));
        asm("v_cvt_pk_bf16_f32 %0, %1, %2" : "=v"(Wd[j][1]) : "v"(sv[base + 2]), "v"(sv[base + 3]));
      }
      #pragma unroll
      for (int ks = 0; ks < 4; ++ks) {
        unsigned s0 = h ? Wd[2 * ks][0] : Wd[2 * ks + 1][0];
        unsigned s1 = h ? Wd[2 * ks][1] : Wd[2 * ks + 1][1];
        unsigned r0 = __shfl_xor(s0, 32);
        unsigned r1 = __shfl_xor(s1, 32);
        unsigned o0 = h ? Wd[2 * ks + 1][0] : Wd[2 * ks][0];
        unsigned o1 = h ? Wd[2 * ks + 1][1] : Wd[2 * ks][1];
        union { unsigned u[4]; short8 s; } fu;
        fu.u[0] = h ? r0 : o0;
        fu.u[1] = h ? r1 : o1;
        fu.u[2] = h ? o0 : r0;
        fu.u[3] = h ? o1 : r1;
        pfrag[qb][ks] = fu.s;
      }
    }

    // ---- PV (swapped)
    #pragma unroll
    for (int db = 0; db < 2; ++db) {
      short8 vf[4];
      #pragma unroll
      for (int ks = 0; ks < 4; ++ks) {
        int row = db * 32 + l31;
        int g = (2 * ks + h) ^ (row & 7);
        vf[ks] = *(const short8*)(ldsV + row * 128 + g * 16);
      }
      __builtin_amdgcn_s_setprio(1);
      #pragma unroll
      for (int qb = 0; qb < 2; ++qb)
        #pragma unroll
        for (int ks = 0; ks < 4; ++ks)
          acc[db][qb] = __builtin_amdgcn_mfma_f32_32x32x16_bf16(
              vf[ks], pfrag[qb][ks], acc[db][qb], 0, 0, 0);
      __builtin_amdgcn_s_setprio(0);
    }

    // ---- tile boundary: counted drain (t+1 resident, t+2 in flight)
    if (st) { SCHED0(); WAIT_VM(4); SCHED0(); }
    else if (kt + 1 < S_ / 64) { SCHED0(); WAIT_VM(0); SCHED0(); }
    SBAR();
  }

  // ---- epilogue
  #pragma unroll
  for (int qb = 0; qb < 2; ++qb) {
    float inv = 1.0f / l_run[qb];
    int q = q0 + qb * 32 + l31;
    float* orow = out + ((long long)b * S_ + q) * H_ + hd * D_;
    #pragma unroll
    for (int db = 0; db < 2; ++db)
      #pragma unroll
      for (int rg = 0; rg < 4; ++rg) {
        f32x4 v4;
        #pragma unroll
        for (int c = 0; c < 4; ++c) v4[c] = acc[db][qb][rg * 4 + c] * inv;
        *(f32x4*)(orow + db * 32 + rg * 8 + 4 * h) = v4;
      }
  }
}

// ---------------- launcher -------------------------------------------------
extern "C" void kernel_launch(void* const* d_in, const int* in_sizes, int n_in,
                              void* d_out, int out_size, void* d_ws, size_t ws_size,
                              hipStream_t stream) {
  const float* X    = (const float*)d_in[0];
  const float* mask = (const float*)d_in[1];
  const float* Wq   = (const float*)d_in[2];
  const float* bq   = (const float*)d_in[3];
  const float* Wk   = (const float*)d_in[4];
  const float* bk   = (const float*)d_in[5];
  const float* Wv   = (const float*)d_in[6];
  const float* bv   = (const float*)d_in[7];
  float* out = (float*)d_out;

  char* ws = (char*)d_ws;
  unsigned short* Xbf = (unsigned short*)ws;                 // 16 MB
  unsigned short* Wbf = (unsigned short*)(ws + 16777216);    //  6 MB
  unsigned short* Qb  = (unsigned short*)(ws + 23068672);    // 16 MB
  unsigned short* Kb  = (unsigned short*)(ws + 39845888);    // 16 MB
  unsigned short* Vt  = (unsigned short*)(ws + 56623104);    // 16 MB

  hipLaunchKernelGGL(cvt_f32_bf16, dim3(2048), dim3(256), 0, stream,
                     X, Wq, Wk, Wv, Xbf, Wbf);
  hipLaunchKernelGGL(qkv_gemm, dim3(768), dim3(512), 0, stream,
                     Xbf, Wbf, bq, bk, bv, Qb, Kb, Vt);
  hipLaunchKernelGGL(attn_fused, dim3(512), dim3(256), 0, stream,
                     Qb, Kb, Vt, mask, out);
}

// Round 9
// 127.520 us; speedup vs baseline: 1.0837x; 1.0432x over previous
//
#include <hip/hip_runtime.h>
#include <hip/hip_bf16.h>
#include <stdint.h>

#define B_ 8
#define S_ 1024
#define NH_ 16
#define D_ 64
#define H_ 1024
#define M_TOT (B_*S_)
#define LOG2E 1.44269504088896f

typedef __attribute__((ext_vector_type(8))) short short8;
typedef __attribute__((ext_vector_type(4))) float f32x4;
typedef __attribute__((ext_vector_type(16))) float f32x16;

#if __has_builtin(__builtin_amdgcn_exp2f)
#define EXP2(x) __builtin_amdgcn_exp2f(x)
#else
#define EXP2(x) __expf((x) * 0.69314718056f)
#endif

static __device__ __forceinline__ unsigned short f2bf(float f) {
  union { float f; unsigned u; } c; c.f = f;
  unsigned u = c.u;
  return (unsigned short)((u + 0x7fffu + ((u >> 16) & 1u)) >> 16);
}

static __device__ __forceinline__ void gld_lds16(void* lds, const void* g) {
  __builtin_amdgcn_global_load_lds((const __attribute__((address_space(1))) unsigned*)g,
                                   (__attribute__((address_space(3))) unsigned*)lds, 16, 0, 0);
}

#define WAIT_LGKM0() asm volatile("s_waitcnt lgkmcnt(0)" ::: "memory")
#define WAIT_VM(n)   asm volatile("s_waitcnt vmcnt(" #n ")" ::: "memory")
#define SBAR()       __builtin_amdgcn_s_barrier()
#define SCHED0()     __builtin_amdgcn_sched_barrier(0)
#define PRIO1()      __builtin_amdgcn_s_setprio(1)
#define PRIO0()      __builtin_amdgcn_s_setprio(0)

// ---------------- kernel 1: f32 -> bf16 conversion (X and the 3 weights) ----
__global__ void cvt_f32_bf16(const float* __restrict__ X,
                             const float* __restrict__ Wq,
                             const float* __restrict__ Wk,
                             const float* __restrict__ Wv,
                             unsigned short* __restrict__ Xbf,
                             unsigned short* __restrict__ Wbf) {
  const long long NX = (long long)M_TOT * H_;
  const long long NW = (long long)H_ * H_;
  long long t = (long long)blockIdx.x * blockDim.x + threadIdx.x;
  const long long stride = (long long)gridDim.x * blockDim.x;
  const long long total4 = (NX + 3 * NW) >> 2;
  for (; t < total4; t += stride) {
    long long e = t << 2;
    const float* src; unsigned short* dst;
    if (e < NX) { src = X + e; dst = Xbf + e; }
    else {
      long long r = e - NX;
      int w = (int)(r / NW);
      long long o = r - (long long)w * NW;
      src = (w == 0 ? Wq : (w == 1 ? Wk : Wv)) + o;
      dst = Wbf + (long long)w * NW + o;
    }
    float4 v = *(const float4*)src;
    ushort4 u;
    u.x = f2bf(v.x); u.y = f2bf(v.y); u.z = f2bf(v.z); u.w = f2bf(v.w);
    *(ushort4*)dst = u;
  }
}

// ---------------- kernel 2: QKV GEMM, 256x256x64, 4-phase counted-vmcnt ----
// 8 waves: wm=w>>2, wn=w&3. Wave rows INTERLEAVED: quadrant ms reads A rows
// [ms*128 + wm*64, +64) -> ALL waves read region-half ms in the same phase
// (likewise B-half ns via cols ns*128 + wn*32). Per-wave output 128x64,
// acc[8][4]. Frag live-set <=64 VGPR (A dead after P2, reused at P3).
// LDS: 2 buf x (A 32KB | B 32KB). Stage slots (1 half-tile = 2 gld_lds/thread
// per phase), operand order per tile t+1: [opA0 @ t-1.P4, opB0 @ t.P1,
// opB1 @ t.P2, opA1 @ t.P3]; P4 of t stages opA0(t+2) into cur buf (reads
// done at P3). Uniform vmcnt(6) (=3 halves) at EVERY phase end -> each half
// is >=4 slots old at first use (ledger verified incl. prologue). Never
// drains to 0 until the post-loop peel of tile 15.
// z=0:Q(scaled /8*log2e) z=1:K z=2:V^T via swapped operand roles.
#define QBM 256
#define QBN 256
#define QBK 64
#define REG_B 32768
#define BUFSZ 65536

#define MMQ(I0, J0, AF, BF)                                               \
  _Pragma("unroll")                                                       \
  for (int a_ = 0; a_ < 4; ++a_)                                          \
    _Pragma("unroll")                                                     \
    for (int b_ = 0; b_ < 2; ++b_)                                        \
      _Pragma("unroll")                                                   \
      for (int k_ = 0; k_ < 2; ++k_)                                      \
        acc[(I0) + a_][(J0) + b_] = __builtin_amdgcn_mfma_f32_16x16x32_bf16( \
            AF[a_][k_], BF[b_][k_], acc[(I0) + a_][(J0) + b_], 0, 0, 0);

#define RD_A(BUF, MS)                                                     \
  _Pragma("unroll")                                                       \
  for (int f_ = 0; f_ < 4; ++f_)                                          \
    _Pragma("unroll")                                                     \
    for (int k_ = 0; k_ < 2; ++k_) A[f_][k_] = rdA(BUF, MS, f_, k_);

#define RD_B(DST, BUF, NS)                                                \
  _Pragma("unroll")                                                       \
  for (int f_ = 0; f_ < 2; ++f_)                                          \
    _Pragma("unroll")                                                     \
    for (int k_ = 0; k_ < 2; ++k_) DST[f_][k_] = rdB(BUF, NS, f_, k_);

__global__ __launch_bounds__(512, 1) void qkv_gemm(
    const unsigned short* __restrict__ Xbf,
    const unsigned short* __restrict__ Wbf,
    const float* __restrict__ bq, const float* __restrict__ bk,
    const float* __restrict__ bv,
    unsigned short* __restrict__ Qo, unsigned short* __restrict__ Ko,
    unsigned short* __restrict__ Vt) {
  __shared__ char lds[2 * BUFSZ];   // 128 KB

  const int tid = threadIdx.x;
  const int w = tid >> 6;
  const int l = tid & 63;
  const int lrow = l & 15, lgrp = l >> 4;
  const int wm = w >> 2, wn = w & 3;

  // XCD x owns m-tiles [4x,4x+4) x all 12 (n,z); nz-major within XCD.
  const int orig = blockIdx.x;          // 0..383
  const int xcd = orig & 7;
  const int slot = orig >> 3;           // 0..47
  const int nz = slot >> 2;             // 0..11
  const int mtile = (xcd * 4 + (slot & 3)) * QBM;
  const int ntile = (nz & 3) * QBN;
  const int z = nz >> 2;

  const unsigned short* Wz = Wbf + (long long)z * H_ * H_;

  const int srow = l >> 3;
  const int sslot = l & 7;
  // stage one region-half (16KB): 2 gld_lds per thread
  auto stageReg = [&](char* buf, int region, int half, int k0) {
    #pragma unroll
    for (int jj = 0; jj < 2; ++jj) {
      int j = w * 2 + jj;                       // 0..15
      int row = half * 128 + j * 8 + srow;
      int so = (sslot ^ (row & 7)) * 8;
      if (region == 0)
        gld_lds16(buf + (half * 16 + j) * 1024,
                  Xbf + (long long)(mtile + row) * H_ + k0 + so);
      else
        gld_lds16(buf + REG_B + (half * 16 + j) * 1024,
                  Wz + (long long)(ntile + row) * H_ + k0 + so);
    }
  };
  auto stageOpA = [&](char* buf, int half, int k0) { stageReg(buf, (z == 2) ? 1 : 0, half, k0); };
  auto stageOpB = [&](char* buf, int half, int k0) { stageReg(buf, (z == 2) ? 0 : 1, half, k0); };

  const int offA = (z == 2) ? REG_B : 0;
  const int offB = (z == 2) ? 0 : REG_B;
  auto rdA = [&](const char* buf, int ms, int fi, int ks) -> short8 {
    int r = ms * 128 + wm * 64 + fi * 16 + lrow;
    return *(const short8*)(buf + offA + r * 128 + (((ks * 4 + lgrp) ^ (r & 7)) * 16));
  };
  auto rdB = [&](const char* buf, int ns, int fj, int ks) -> short8 {
    int r = ns * 128 + wn * 32 + fj * 16 + lrow;
    return *(const short8*)(buf + offB + r * 128 + (((ks * 4 + lgrp) ^ (r & 7)) * 16));
  };

  f32x4 acc[8][4];
  f32x4 zero = {0.f, 0.f, 0.f, 0.f};
  #pragma unroll
  for (int a = 0; a < 8; ++a)
    #pragma unroll
    for (int c = 0; c < 4; ++c) acc[a][c] = zero;

  short8 A[4][2], B0[2][2], B1[2][2];

  // prologue ledger: [t0.A0, t0.B0, t0.B1, t0.A1, t1.A0] then vmcnt(6)
  stageOpA(lds, 0, 0);
  stageOpB(lds, 0, 0);
  stageOpB(lds, 1, 0);
  stageOpA(lds, 1, 0);
  stageOpA(lds + BUFSZ, 0, QBK);
  SCHED0(); WAIT_VM(6); SCHED0();
  SBAR();

  #pragma unroll 1
  for (int t = 0; t < 15; ++t) {
    char* bc = lds + ((t & 1) ? BUFSZ : 0);
    char* bn = lds + ((t & 1) ? 0 : BUFSZ);
    const int k1 = (t + 1) * QBK;
    const int k2 = (t + 2) * QBK;
    const bool st2 = (t + 2 < 16);

    // ---- P1: reads A(ms0)+B(ns0); stage opB0(t+1); MFMA Q(0,0)
    RD_A(bc, 0);
    RD_B(B0, bc, 0);
    stageOpB(bn, 0, k1);
    WAIT_LGKM0(); SCHED0();
    PRIO1(); MMQ(0, 0, A, B0); PRIO0();
    SCHED0(); WAIT_VM(6); SCHED0();
    SBAR();

    // ---- P2: reads B(ns1); stage opB1(t+1); MFMA Q(0,1)
    RD_B(B1, bc, 1);
    stageOpB(bn, 1, k1);
    WAIT_LGKM0(); SCHED0();
    PRIO1(); MMQ(0, 2, A, B1); PRIO0();
    SCHED0(); WAIT_VM(6); SCHED0();
    SBAR();

    // ---- P3: reads A(ms1); stage opA1(t+1); MFMA Q(1,1)
    RD_A(bc, 1);
    stageOpA(bn, 1, k1);
    WAIT_LGKM0(); SCHED0();
    PRIO1(); MMQ(4, 2, A, B1); PRIO0();
    SCHED0(); WAIT_VM(6); SCHED0();
    SBAR();

    // ---- P4: no reads; stage opA0(t+2) into cur buf; MFMA Q(1,0)
    if (st2) stageOpA(bc, 0, k2);
    PRIO1(); MMQ(4, 0, A, B0); PRIO0();
    SCHED0(); WAIT_VM(6); SCHED0();
    SBAR();
  }

  // ---- drain + peeled tile 15 (buf parity: odd -> lds+BUFSZ)
  SCHED0(); WAIT_VM(0); SCHED0();
  SBAR();
  {
    char* bc = lds + BUFSZ;
    RD_A(bc, 0);
    RD_B(B0, bc, 0);
    WAIT_LGKM0(); SCHED0();
    PRIO1(); MMQ(0, 0, A, B0); PRIO0();
    RD_B(B1, bc, 1);
    WAIT_LGKM0(); SCHED0();
    PRIO1(); MMQ(0, 2, A, B1); PRIO0();
    RD_A(bc, 1);
    WAIT_LGKM0(); SCHED0();
    PRIO1(); MMQ(4, 2, A, B1); MMQ(4, 0, A, B0); PRIO0();
  }

  // ---- epilogue: acc[mi][nj], mi=ms*4+fi, nj=ns*2+fj
  const float* bias = (z == 0) ? bq : (z == 1) ? bk : bv;
  if (z != 2) {
    unsigned short* O = (z == 0) ? Qo : Ko;
    #pragma unroll
    for (int nj = 0; nj < 4; ++nj) {
      int n = ntile + (nj >> 1) * 128 + wn * 32 + (nj & 1) * 16 + lrow;
      float bv_ = bias[n];
      int h = n >> 6, d = n & 63;
      #pragma unroll
      for (int mi = 0; mi < 8; ++mi)
        #pragma unroll
        for (int r = 0; r < 4; ++r) {
          int m = mtile + (mi >> 2) * 128 + wm * 64 + (mi & 3) * 16 + lgrp * 4 + r;
          float val = acc[mi][nj][r] + bv_;
          if (z == 0) val *= 0.125f * LOG2E;
          int b = m >> 10, s = m & 1023;
          O[(((long long)(b * NH_ + h)) * S_ + s) * D_ + d] = f2bf(val);
        }
    }
  } else {
    #pragma unroll
    for (int mi = 0; mi < 8; ++mi)
      #pragma unroll
      for (int r = 0; r < 4; ++r) {
        int nfull = ntile + (mi >> 2) * 128 + wm * 64 + (mi & 3) * 16 + lgrp * 4 + r; // d-side (W rows)
        float bv_ = bias[nfull];
        int h = nfull >> 6, d = nfull & 63;
        #pragma unroll
        for (int nj = 0; nj < 4; ++nj) {
          int mfull = mtile + (nj >> 1) * 128 + wn * 32 + (nj & 1) * 16 + lrow;        // s-side (X rows)
          float val = acc[mi][nj][r] + bv_;
          int b = mfull >> 10, s = mfull & 1023;
          Vt[(((long long)(b * NH_ + h)) * D_ + d) * S_ + s] = f2bf(val);
        }
      }
  }
}

// ---------------- kernel 3: fused flash attention (unchanged from R8) ------
__global__ __launch_bounds__(256, 2) void attn_fused(
    const unsigned short* __restrict__ Qbf,
    const unsigned short* __restrict__ Kbf,
    const unsigned short* __restrict__ Vtb,
    const float* __restrict__ mask,
    float* __restrict__ out) {
  __shared__ char lds[3 * 16384 + 4096];      // 3 KV buffers | mask row
  char* ldsM = lds + 49152;
  const int tid = threadIdx.x, w = tid >> 6, l = tid & 63;
  const int l31 = l & 31, h = l >> 5;

  const int lid = blockIdx.x;                 // 0..511
  const int xcd = lid & 7, k8 = lid >> 3;
  const int bh = xcd * 16 + (k8 >> 2);
  const int qt = k8 & 3;
  const int b = bh >> 4, hd = bh & 15;
  const int q0 = qt * 256 + w * 64;

  const unsigned short* Kg = Kbf + (long long)bh * S_ * D_;
  const unsigned short* Vg = Vtb + (long long)bh * D_ * S_;
  const float* mrow = mask + b * S_;

  auto stageKV = [&](int kt, char* buf) {
    const int key0 = kt * 64;
    #pragma unroll
    for (int t = 0; t < 2; ++t) {
      int j = w * 2 + t;
      int row = j * 8 + (l >> 3);
      int so = ((l & 7) ^ (row & 7)) * 8;
      gld_lds16(buf + j * 1024,        Kg + (long long)(key0 + row) * D_ + so);
      gld_lds16(buf + 8192 + j * 1024, Vg + (long long)row * S_ + key0 + so);
    }
  };

  short8 qf[2][4];
  #pragma unroll
  for (int qb = 0; qb < 2; ++qb)
    #pragma unroll
    for (int ks = 0; ks < 4; ++ks)
      qf[qb][ks] = *(const short8*)(Qbf + ((long long)bh * S_ + q0 + qb * 32 + l31) * D_ + ks * 16 + 8 * h);
  gld_lds16(ldsM + w * 1024, mrow + w * 256 + l * 4);
  SCHED0(); WAIT_VM(0); SCHED0();

  stageKV(0, lds);
  stageKV(1, lds + 16384);
  SCHED0(); WAIT_VM(4); SCHED0();
  SBAR();

  f32x16 acc[2][2];
  #pragma unroll
  for (int db = 0; db < 2; ++db)
    #pragma unroll
    for (int qb = 0; qb < 2; ++qb)
      #pragma unroll
      for (int r = 0; r < 16; ++r) acc[db][qb][r] = 0.f;
  float m_run[2] = {-1e30f, -1e30f};
  float l_run[2] = {0.f, 0.f};

  #pragma unroll 1
  for (int kt = 0; kt < S_ / 64; ++kt) {
    char* ldsK = lds + (kt % 3) * 16384;
    char* ldsV = ldsK + 8192;
    const int key0 = kt * 64;
    const bool st = (kt + 2 < S_ / 64);

    if (st) stageKV(kt + 2, lds + ((kt + 2) % 3) * 16384);

    f32x16 sc[2][2];
    #pragma unroll
    for (int kb = 0; kb < 2; ++kb)
      #pragma unroll
      for (int qb = 0; qb < 2; ++qb)
        #pragma unroll
        for (int r = 0; r < 16; ++r) sc[kb][qb][r] = 0.f;

    #pragma unroll
    for (int kb = 0; kb < 2; ++kb) {
      short8 kf[4];
      #pragma unroll
      for (int ks = 0; ks < 4; ++ks) {
        int row = kb * 32 + l31;
        int g = (2 * ks + h) ^ (row & 7);
        kf[ks] = *(const short8*)(ldsK + row * 128 + g * 16);
      }
      __builtin_amdgcn_s_setprio(1);
      #pragma unroll
      for (int qb = 0; qb < 2; ++qb)
        #pragma unroll
        for (int ks = 0; ks < 4; ++ks)
          sc[kb][qb] = __builtin_amdgcn_mfma_f32_32x32x16_bf16(
              kf[ks], qf[qb][ks], sc[kb][qb], 0, 0, 0);
      __builtin_amdgcn_s_setprio(0);
    }

    short8 pfrag[2][4];
    #pragma unroll
    for (int qb = 0; qb < 2; ++qb) {
      float sv[32];
      #pragma unroll
      for (int kb = 0; kb < 2; ++kb)
        #pragma unroll
        for (int rg = 0; rg < 4; ++rg) {
          f32x4 m4 = *(const f32x4*)(ldsM + (key0 + kb * 32 + rg * 8 + 4 * h) * 4);
          #pragma unroll
          for (int c = 0; c < 4; ++c)
            sv[kb * 16 + rg * 4 + c] = fmaf(m4[c], LOG2E, sc[kb][qb][rg * 4 + c]);
        }
      float r16[16];
      #pragma unroll
      for (int i = 0; i < 16; ++i) r16[i] = fmaxf(sv[i], sv[i + 16]);
      #pragma unroll
      for (int i = 0; i < 8; ++i) r16[i] = fmaxf(r16[i], r16[i + 8]);
      #pragma unroll
      for (int i = 0; i < 4; ++i) r16[i] = fmaxf(r16[i], r16[i + 4]);
      float pm = fmaxf(fmaxf(r16[0], r16[1]), fmaxf(r16[2], r16[3]));
      pm = fmaxf(pm, __shfl_xor(pm, 32));
      if (!__all(pm - m_run[qb] <= 11.5f)) {
        float mn = fmaxf(m_run[qb], pm);
        float rs = EXP2(m_run[qb] - mn);
        m_run[qb] = mn;
        l_run[qb] *= rs;
        #pragma unroll
        for (int db = 0; db < 2; ++db)
          #pragma unroll
          for (int r = 0; r < 16; ++r) acc[db][qb][r] *= rs;
      }
      const float mcur = m_run[qb];
      #pragma unroll
      for (int i = 0; i < 32; ++i) sv[i] = EXP2(sv[i] - mcur);
      #pragma unroll
      for (int i = 0; i < 16; ++i) r16[i] = sv[i] + sv[i + 16];
      #pragma unroll
      for (int i = 0; i < 8; ++i) r16[i] = r16[i] + r16[i + 8];
      #pragma unroll
      for (int i = 0; i < 4; ++i) r16[i] = r16[i] + r16[i + 4];
      float ps = (r16[0] + r16[1]) + (r16[2] + r16[3]);
      ps += __shfl_xor(ps, 32);
      l_run[qb] += ps;

      unsigned Wd[8][2];
      #pragma unroll
      for (int j = 0; j < 8; ++j) {
        int base = (j >> 2) * 16 + (j & 3) * 4;
        asm("v_cvt_pk_bf16_f32 %0, %1, %2" : "=v"(Wd[j][0]) : "v"(sv[base + 0]), "v"(sv[base + 1]));
        asm("v_cvt_pk_bf16_f32 %0, %1, %2" : "=v"(Wd[j][1]) : "v"(sv[base + 2]), "v"(sv[base + 3]));
      }
      #pragma unroll
      for (int ks = 0; ks < 4; ++ks) {
        unsigned s0 = h ? Wd[2 * ks][0] : Wd[2 * ks + 1][0];
        unsigned s1 = h ? Wd[2 * ks][1] : Wd[2 * ks + 1][1];
        unsigned r0 = __shfl_xor(s0, 32);
        unsigned r1 = __shfl_xor(s1, 32);
        unsigned o0 = h ? Wd[2 * ks + 1][0] : Wd[2 * ks][0];
        unsigned o1 = h ? Wd[2 * ks + 1][1] : Wd[2 * ks][1];
        union { unsigned u[4]; short8 s; } fu;
        fu.u[0] = h ? r0 : o0;
        fu.u[1] = h ? r1 : o1;
        fu.u[2] = h ? o0 : r0;
        fu.u[3] = h ? o1 : r1;
        pfrag[qb][ks] = fu.s;
      }
    }

    #pragma unroll
    for (int db = 0; db < 2; ++db) {
      short8 vf[4];
      #pragma unroll
      for (int ks = 0; ks < 4; ++ks) {
        int row = db * 32 + l31;
        int g = (2 * ks + h) ^ (row & 7);
        vf[ks] = *(const short8*)(ldsV + row * 128 + g * 16);
      }
      __builtin_amdgcn_s_setprio(1);
      #pragma unroll
      for (int qb = 0; qb < 2; ++qb)
        #pragma unroll
        for (int ks = 0; ks < 4; ++ks)
          acc[db][qb] = __builtin_amdgcn_mfma_f32_32x32x16_bf16(
              vf[ks], pfrag[qb][ks], acc[db][qb], 0, 0, 0);
      __builtin_amdgcn_s_setprio(0);
    }

    if (st) { SCHED0(); WAIT_VM(4); SCHED0(); }
    else if (kt + 1 < S_ / 64) { SCHED0(); WAIT_VM(0); SCHED0(); }
    SBAR();
  }

  #pragma unroll
  for (int qb = 0; qb < 2; ++qb) {
    float inv = 1.0f / l_run[qb];
    int q = q0 + qb * 32 + l31;
    float* orow = out + ((long long)b * S_ + q) * H_ + hd * D_;
    #pragma unroll
    for (int db = 0; db < 2; ++db)
      #pragma unroll
      for (int rg = 0; rg < 4; ++rg) {
        f32x4 v4;
        #pragma unroll
        for (int c = 0; c < 4; ++c) v4[c] = acc[db][qb][rg * 4 + c] * inv;
        *(f32x4*)(orow + db * 32 + rg * 8 + 4 * h) = v4;
      }
  }
}

// ---------------- launcher -------------------------------------------------
extern "C" void kernel_launch(void* const* d_in, const int* in_sizes, int n_in,
                              void* d_out, int out_size, void* d_ws, size_t ws_size,
                              hipStream_t stream) {
  const float* X    = (const float*)d_in[0];
  const float* mask = (const float*)d_in[1];
  const float* Wq   = (const float*)d_in[2];
  const float* bq   = (const float*)d_in[3];
  const float* Wk   = (const float*)d_in[4];
  const float* bk   = (const float*)d_in[5];
  const float* Wv   = (const float*)d_in[6];
  const float* bv   = (const float*)d_in[7];
  float* out = (float*)d_out;

  char* ws = (char*)d_ws;
  unsigned short* Xbf = (unsigned short*)ws;                 // 16 MB
  unsigned short* Wbf = (unsigned short*)(ws + 16777216);    //  6 MB
  unsigned short* Qb  = (unsigned short*)(ws + 23068672);    // 16 MB
  unsigned short* Kb  = (unsigned short*)(ws + 39845888);    // 16 MB
  unsigned short* Vt  = (unsigned short*)(ws + 56623104);    // 16 MB

  hipLaunchKernelGGL(cvt_f32_bf16, dim3(2048), dim3(256), 0, stream,
                     X, Wq, Wk, Wv, Xbf, Wbf);
  hipLaunchKernelGGL(qkv_gemm, dim3(384), dim3(512), 0, stream,
                     Xbf, Wbf, bq, bk, bv, Qb, Kb, Vt);
  hipLaunchKernelGGL(attn_fused, dim3(512), dim3(256), 0, stream,
                     Qb, Kb, Vt, mask, out);
}